// Round 1
// baseline (1466.829 us; speedup 1.0000x reference)
//
#include <hip/hip_runtime.h>
#include <hip/hip_bf16.h>

// Problem constants (from reference)
#define B_    64
#define T_    1000
#define IN_   257
#define HID_  40
#define G3_   120      // 3*HID
#define OUT_  257
#define M_    (B_*T_)  // 64000 rows
#define NGI_  480      // 4 * 120 (f0|f1|b0|b1)
#define KP_   720      // 80 silu + 80*8 spline
// ws layout (bf16 intermediates): gi 64000x480 (61.44MB) | P 64000x720 (92.16MB) | Wkan 257x720 (0.37MB)
#define OFF_P  61440000ull
#define OFF_WK (61440000ull + 92160000ull)

__device__ __forceinline__ float sigf(float x){ return 1.0f/(1.0f + __expf(-x)); }
__device__ __forceinline__ float tanhfast(float x){ return 1.0f - 2.0f/(__expf(2.0f*x)+1.0f); }
// grid[p] = (p-3)*0.4f - 1.0f, p = 0..11  (matches jnp.arange(-3,9)*0.4 - 1 in f32)
__device__ __forceinline__ float gridp(int p){ return (float)(p-3)*0.4f - 1.0f; }

__device__ __forceinline__ void bspline8(float x, float* o){
    float b[11];
#pragma unroll
    for (int p=0;p<11;p++) b[p] = (x >= gridp(p) && x < gridp(p+1)) ? 1.0f : 0.0f;
#pragma unroll
    for (int k=1;k<=3;k++){
#pragma unroll
        for (int j=0;j<=10-k;j++){
            float gj=gridp(j), gjk=gridp(j+k), gjk1=gridp(j+k+1), gj1=gridp(j+1);
            b[j] = (x-gj)/(gjk-gj)*b[j] + (gjk1-x)/(gjk1-gj1)*b[j+1];
        }
    }
#pragma unroll
    for (int m=0;m<8;m++) o[m]=b[m];
}

// Pack Wkan[o, 0:80] = base_weight[o,:]; Wkan[o, 80+i*8+m] = spline_weight[o,i,m]*scaler[o,i]
__global__ __launch_bounds__(256) void kprep(const float* __restrict__ bw,
                                             const float* __restrict__ sw,
                                             const float* __restrict__ ss,
                                             __hip_bfloat16* __restrict__ wk){
    int idx = blockIdx.x*256 + threadIdx.x;
    if (idx >= OUT_*KP_) return;
    int o = idx / KP_, k = idx % KP_;
    float v;
    if (k < 80) v = bw[o*80 + k];
    else { int i = (k-80)>>3, m = (k-80)&7; v = sw[(o*80+i)*8 + m] * ss[o*80+i]; }
    wk[idx] = __float2bfloat16(v);
}

// GEMM1: gi[m,n] = sum_k X[m,k]*W[n,k] + bias[n];  n<240 -> Wih_f (flat 240x257), else Wih_b
__global__ __launch_bounds__(256) void k1_gemm(const float* __restrict__ X,
                                               const float* __restrict__ Wf,
                                               const float* __restrict__ Wb,
                                               const float* __restrict__ bf,
                                               const float* __restrict__ bb,
                                               __hip_bfloat16* __restrict__ gi){
    __shared__ float As[16][65];
    __shared__ float Bs[16][65];
    int tid = threadIdx.x;
    int m0 = blockIdx.y*64, n0 = blockIdx.x*64;
    int tx = tid & 15, ty = tid >> 4;
    float acc[4][4] = {};
    for (int k0=0;k0<IN_;k0+=16){
#pragma unroll
        for (int p=0;p<4;p++){
            int idx = tid + p*256;
            int r = idx >> 4, c = idx & 15;
            int kk = k0 + c;
            As[c][r] = (kk < IN_) ? X[(size_t)(m0+r)*IN_ + kk] : 0.0f;
        }
#pragma unroll
        for (int p=0;p<4;p++){
            int idx = tid + p*256;
            int r = idx >> 4, c = idx & 15;
            int n = n0 + r, kk = k0 + c;
            float v = 0.0f;
            if (n < NGI_ && kk < IN_)
                v = (n < 240) ? Wf[(size_t)n*IN_ + kk] : Wb[(size_t)(n-240)*IN_ + kk];
            Bs[c][r] = v;
        }
        __syncthreads();
#pragma unroll
        for (int k=0;k<16;k++){
            float a[4], b[4];
#pragma unroll
            for (int i=0;i<4;i++) a[i] = As[k][ty*4+i];
#pragma unroll
            for (int j=0;j<4;j++) b[j] = Bs[k][tx*4+j];
#pragma unroll
            for (int i=0;i<4;i++)
#pragma unroll
                for (int j=0;j<4;j++) acc[i][j] += a[i]*b[j];
        }
        __syncthreads();
    }
#pragma unroll
    for (int i=0;i<4;i++){
        int m = m0 + ty*4 + i;
#pragma unroll
        for (int j=0;j<4;j++){
            int n = n0 + tx*4 + j;
            if (n < NGI_){
                float bias = (n < 240) ? bf[n] : bb[n-240];
                gi[(size_t)m*NGI_ + n] = __float2bfloat16(acc[i][j] + bias);
            }
        }
    }
}

// Pointwise GRU (both layers, both directions) + silu/bspline feature build -> P(64000x720)
__global__ __launch_bounds__(256) void k2_gru(const __hip_bfloat16* __restrict__ gi,
                                              const float* __restrict__ Whh_f,
                                              const float* __restrict__ bhh_f,
                                              const float* __restrict__ Whh_b,
                                              const float* __restrict__ bhh_b,
                                              __hip_bfloat16* __restrict__ P){
    __shared__ float h0_lds[HID_][256];   // [j][tid] conflict-free for dynamic h0[j] access
    int gid = blockIdx.x*256 + threadIdx.x;
    if (gid >= 2*M_) return;
    int dir = gid / M_;          // wave-uniform: M_ % 64 == 0
    int m   = gid % M_;
    int b = m / T_, t = m % T_;
    int src = (dir == 0) ? m : (b*T_ + (T_-1-t));    // backward reads reversed-time gi
    const __hip_bfloat16* row = gi + (size_t)src*NGI_ + dir*240;
    const float* Whh1 = ((dir==0) ? Whh_f : Whh_b) + G3_*HID_;  // layer 1
    const float* bhh0 = (dir==0) ? bhh_f : bhh_b;
    const float* bhh1 = bhh0 + G3_;

    float h0[HID_];
#pragma unroll
    for (int j=0;j<HID_;j++){
        float ir = __bfloat162float(row[j]);
        float iz = __bfloat162float(row[40+j]);
        float in = __bfloat162float(row[80+j]);
        float r = sigf(ir + bhh0[j]);
        float z = sigf(iz + bhh0[40+j]);
        float n = tanhfast(in + r*bhh0[80+j]);
        h0[j] = (1.0f - z)*n;          // h_prev = 0
        h0_lds[j][threadIdx.x] = h0[j];
    }
    __hip_bfloat16* Prow = P + (size_t)m*KP_;
    int fbase = dir*HID_;
    for (int j=0;j<HID_;j++){
        float gr = bhh1[j], gz = bhh1[40+j], gn = bhh1[80+j];
#pragma unroll
        for (int k=0;k<HID_;k++){
            float h = h0[k];
            gr += Whh1[j*HID_+k]      * h;
            gz += Whh1[(40+j)*HID_+k] * h;
            gn += Whh1[(80+j)*HID_+k] * h;
        }
        float ir = __bfloat162float(row[120+j]);
        float iz = __bfloat162float(row[160+j]);
        float in = __bfloat162float(row[200+j]);
        float r = sigf(ir + gr);
        float z = sigf(iz + gz);
        float n = tanhfast(in + r*gn);
        float h1 = (1.0f - z)*n + z*h0_lds[j][threadIdx.x];
        int fi = fbase + j;
        Prow[fi] = __float2bfloat16(h1 * sigf(h1));   // silu(feat)
        float bb8[8];
        bspline8(h1, bb8);
#pragma unroll
        for (int mm=0;mm<8;mm++) Prow[80 + fi*8 + mm] = __float2bfloat16(bb8[mm]);
    }
}

// GEMM2: out[m,o] = 1.2*sigmoid(slope[o] * sum_k P[m,k]*Wk[o,k])
__global__ __launch_bounds__(256) void k3_gemm(const __hip_bfloat16* __restrict__ P,
                                               const __hip_bfloat16* __restrict__ Wk,
                                               const float* __restrict__ slope,
                                               float* __restrict__ outp){
    __shared__ float As[16][65];
    __shared__ float Bs[16][65];
    int tid = threadIdx.x;
    int m0 = blockIdx.y*64, n0 = blockIdx.x*64;
    int tx = tid & 15, ty = tid >> 4;
    float acc[4][4] = {};
    for (int k0=0;k0<KP_;k0+=16){
#pragma unroll
        for (int p=0;p<4;p++){
            int idx = tid + p*256;
            int r = idx >> 4, c = idx & 15;
            As[c][r] = __bfloat162float(P[(size_t)(m0+r)*KP_ + k0 + c]);
        }
#pragma unroll
        for (int p=0;p<4;p++){
            int idx = tid + p*256;
            int r = idx >> 4, c = idx & 15;
            int n = n0 + r;
            Bs[c][r] = (n < OUT_) ? __bfloat162float(Wk[(size_t)n*KP_ + k0 + c]) : 0.0f;
        }
        __syncthreads();
#pragma unroll
        for (int k=0;k<16;k++){
            float a[4], b[4];
#pragma unroll
            for (int i=0;i<4;i++) a[i] = As[k][ty*4+i];
#pragma unroll
            for (int j=0;j<4;j++) b[j] = Bs[k][tx*4+j];
#pragma unroll
            for (int i=0;i<4;i++)
#pragma unroll
                for (int j=0;j<4;j++) acc[i][j] += a[i]*b[j];
        }
        __syncthreads();
    }
#pragma unroll
    for (int i=0;i<4;i++){
        int m = m0 + ty*4 + i;
#pragma unroll
        for (int j=0;j<4;j++){
            int n = n0 + tx*4 + j;
            if (n < OUT_)
                outp[(size_t)m*OUT_ + n] = 1.2f * sigf(slope[n]*acc[i][j]);
        }
    }
}

extern "C" void kernel_launch(void* const* d_in, const int* in_sizes, int n_in,
                              void* d_out, int out_size, void* d_ws, size_t ws_size,
                              hipStream_t stream) {
    const float* x      = (const float*)d_in[0];
    const float* Wih_f  = (const float*)d_in[1];
    const float* Whh_f  = (const float*)d_in[2];
    const float* bih_f  = (const float*)d_in[3];
    const float* bhh_f  = (const float*)d_in[4];
    const float* Wih_b  = (const float*)d_in[5];
    const float* Whh_b  = (const float*)d_in[6];
    const float* bih_b  = (const float*)d_in[7];
    const float* bhh_b  = (const float*)d_in[8];
    const float* base_w = (const float*)d_in[9];
    const float* spl_w  = (const float*)d_in[10];
    const float* spl_s  = (const float*)d_in[11];
    const float* slope  = (const float*)d_in[12];
    // d_in[13] = lengths (all == T, unused by reference math)

    char* ws = (char*)d_ws;
    __hip_bfloat16* gi = (__hip_bfloat16*)ws;
    __hip_bfloat16* P  = (__hip_bfloat16*)(ws + OFF_P);
    __hip_bfloat16* Wk = (__hip_bfloat16*)(ws + OFF_WK);
    float* outp = (float*)d_out;

    hipLaunchKernelGGL(kprep, dim3((OUT_*KP_ + 255)/256), dim3(256), 0, stream,
                       base_w, spl_w, spl_s, Wk);
    hipLaunchKernelGGL(k1_gemm, dim3(8, 1000), dim3(256), 0, stream,
                       x, Wih_f, Wih_b, bih_f, bih_b, gi);
    hipLaunchKernelGGL(k2_gru, dim3((2*M_ + 255)/256), dim3(256), 0, stream,
                       gi, Whh_f, bhh_f, Whh_b, bhh_b, P);
    hipLaunchKernelGGL(k3_gemm, dim3(5, 1000), dim3(256), 0, stream,
                       P, Wk, slope, outp);
}

// Round 2
// 655.465 us; speedup vs baseline: 2.2378x; 2.2378x over previous
//
#include <hip/hip_runtime.h>
#include <hip/hip_bf16.h>

// Problem constants
#define B_    64
#define T_    1000
#define IN_   257
#define HID_  40
#define G3_   120
#define OUT_  257
#define M_    (B_*T_)   // 64000
#define NGI_  480       // 4*120: f0|f1|b0|b1
#define KP_   736       // padded KAN feature dim (720 real)
#define KP1_  288       // padded GEMM1 K (257 real)
#define NP_   272       // padded OUT_ for k3

// ws layout:
// gi  64000x480 bf16 = 61,440,000
// P   64000x736 bf16 = 94,208,000
// Wk  272x736  bf16  =    400,384
// Wb  480x288  bf16  =    276,480
#define OFF_P   61440000ull
#define OFF_WK  (61440000ull + 94208000ull)
#define OFF_WB  (OFF_WK + 400384ull)

typedef __attribute__((ext_vector_type(8))) short short8;   // 8 bf16 = 4 VGPR
typedef __attribute__((ext_vector_type(4))) float f32x4;    // MFMA C/D

__device__ __forceinline__ float sigf(float x){ return 1.0f/(1.0f + __expf(-x)); }
__device__ __forceinline__ float tanhfast(float x){ return 1.0f - 2.0f/(__expf(2.0f*x)+1.0f); }
__device__ __forceinline__ float gridp(int p){ return (float)(p-3)*0.4f - 1.0f; }

__device__ __forceinline__ void bspline8(float x, float* o){
    float b[11];
#pragma unroll
    for (int p=0;p<11;p++) b[p] = (x >= gridp(p) && x < gridp(p+1)) ? 1.0f : 0.0f;
#pragma unroll
    for (int k=1;k<=3;k++){
#pragma unroll
        for (int j=0;j<=10-k;j++){
            float gj=gridp(j), gjk=gridp(j+k), gjk1=gridp(j+k+1), gj1=gridp(j+1);
            b[j] = (x-gj)/(gjk-gj)*b[j] + (gjk1-x)/(gjk1-gj1)*b[j+1];
        }
    }
#pragma unroll
    for (int m=0;m<8;m++) o[m]=b[m];
}

__device__ __forceinline__ short bfbits(float v){
    __hip_bfloat16 h = __float2bfloat16(v);
    return *(short*)&h;
}

// Pack Wk[272][736] bf16: Wk[o,0:80]=base_weight, Wk[o,80+i*8+m]=spline_weight*scaler, pad zeros
__global__ __launch_bounds__(256) void kprep(const float* __restrict__ bw,
                                             const float* __restrict__ sw,
                                             const float* __restrict__ ss,
                                             __hip_bfloat16* __restrict__ wk){
    int idx = blockIdx.x*256 + threadIdx.x;     // one 8-elem chunk
    if (idx >= NP_*(KP_/8)) return;
    int o = idx / (KP_/8), q = idx % (KP_/8);
    short8 pk;
#pragma unroll
    for (int e=0;e<8;e++){
        int k = q*8 + e;
        float v = 0.0f;
        if (o < OUT_ && k < 720){
            if (k < 80) v = bw[o*80 + k];
            else { int i = (k-80)>>3, m = (k-80)&7; v = sw[(o*80+i)*8 + m] * ss[o*80+i]; }
        }
        pk[e] = bfbits(v);
    }
    *(short8*)((void*)&wk[(size_t)o*KP_ + q*8]) = pk;
}

// Pack Wb[480][288] bf16 from Wih_f(240x257) | Wih_b(240x257), zero-pad K
__global__ __launch_bounds__(256) void wprep(const float* __restrict__ Wf,
                                             const float* __restrict__ Wbk,
                                             __hip_bfloat16* __restrict__ wb){
    int idx = blockIdx.x*256 + threadIdx.x;
    if (idx >= NGI_*(KP1_/8)) return;
    int n = idx / (KP1_/8), q = idx % (KP1_/8);
    short8 pk;
#pragma unroll
    for (int e=0;e<8;e++){
        int k = q*8 + e;
        float v = 0.0f;
        if (k < IN_) v = (n < 240) ? Wf[(size_t)n*IN_ + k] : Wbk[(size_t)(n-240)*IN_ + k];
        pk[e] = bfbits(v);
    }
    *(short8*)((void*)&wb[(size_t)n*KP1_ + q*8]) = pk;
}

// GEMM1 (MFMA): gi[m,n] = sum_k X[m,k]*Wb[n,k] + bias[n]
// block: 256 thr / 4 waves; M-tile 128 (2 subtiles per wave), N-tile 160 (10 n-tiles)
__global__ __launch_bounds__(256) void k1_gemm(const float* __restrict__ X,
                                               const __hip_bfloat16* __restrict__ Wb16,
                                               const float* __restrict__ bf,
                                               const float* __restrict__ bb,
                                               __hip_bfloat16* __restrict__ gi){
    __shared__ __hip_bfloat16 Asm[128*40];
    __shared__ __hip_bfloat16 Bsm[160*40];
    int tid = threadIdx.x, wave = tid>>6, lane = tid&63;
    int m0 = blockIdx.y*128, n0 = blockIdx.x*160;
    f32x4 acc[2][10];
#pragma unroll
    for (int s=0;s<2;s++)
#pragma unroll
        for (int j=0;j<10;j++) acc[s][j] = (f32x4){0.f,0.f,0.f,0.f};

    for (int k0=0;k0<KP1_;k0+=32){
#pragma unroll
        for (int p=0;p<2;p++){                    // A: 512 chunks, fp32->bf16 convert
            int c = tid + p*256;
            int row = c>>2, kc = (c&3)*8;
            short8 pk;
#pragma unroll
            for (int e=0;e<8;e++){
                int k = k0 + kc + e;
                float v = (k < IN_) ? X[(size_t)(m0+row)*IN_ + k] : 0.0f;
                pk[e] = bfbits(v);
            }
            *(short8*)((void*)&Asm[row*40 + kc]) = pk;
        }
#pragma unroll
        for (int p=0;p<3;p++){                    // B: 640 chunks
            int c = tid + p*256;
            if (c < 640){
                int row = c>>2, kc = (c&3)*8;
                *(short8*)((void*)&Bsm[row*40 + kc]) =
                    *(const short8*)&Wb16[(size_t)(n0+row)*KP1_ + k0 + kc];
            }
        }
        __syncthreads();
        int kf = (lane>>4)*8, rl = lane&15;
        short8 a0 = *(short8*)((void*)&Asm[(wave*32 + rl)*40 + kf]);
        short8 a1 = *(short8*)((void*)&Asm[(wave*32 + 16 + rl)*40 + kf]);
#pragma unroll
        for (int j=0;j<10;j++){
            short8 b = *(short8*)((void*)&Bsm[(j*16 + rl)*40 + kf]);
            acc[0][j] = __builtin_amdgcn_mfma_f32_16x16x32_bf16(a0, b, acc[0][j], 0,0,0);
            acc[1][j] = __builtin_amdgcn_mfma_f32_16x16x32_bf16(a1, b, acc[1][j], 0,0,0);
        }
        __syncthreads();
    }
    int rl = lane&15, quad = lane>>4;
#pragma unroll
    for (int j=0;j<10;j++){
        int n = n0 + j*16 + rl;
        float bias = (n < 240) ? bf[n] : bb[n-240];
#pragma unroll
        for (int s=0;s<2;s++){
            int mb = m0 + wave*32 + s*16 + quad*4;
#pragma unroll
            for (int r=0;r<4;r++)
                gi[(size_t)(mb+r)*NGI_ + n] = __float2bfloat16(acc[s][j][r] + bias);
        }
    }
}

// Pointwise GRU + feature build -> P(64000x736 bf16)
__global__ __launch_bounds__(256) void k2_gru(const __hip_bfloat16* __restrict__ gi,
                                              const float* __restrict__ Whh_f,
                                              const float* __restrict__ bhh_f,
                                              const float* __restrict__ Whh_b,
                                              const float* __restrict__ bhh_b,
                                              __hip_bfloat16* __restrict__ P){
    __shared__ float h0_lds[HID_][256];
    int dir = (blockIdx.x >= 250) ? 1 : 0;       // block-uniform -> scalar loads of Whh
    int m = (blockIdx.x - dir*250)*256 + threadIdx.x;
    int b = m / T_, t = m % T_;
    int src = dir ? (b*T_ + (T_-1-t)) : m;
    const __hip_bfloat16* row = gi + (size_t)src*NGI_ + dir*240;
    const float* Whh1 = (dir ? Whh_b : Whh_f) + G3_*HID_;
    const float* bhh0 = dir ? bhh_b : bhh_f;
    const float* bhh1 = bhh0 + G3_;

    float h0[HID_];
#pragma unroll
    for (int j=0;j<HID_;j++){
        float ir = __bfloat162float(row[j]);
        float iz = __bfloat162float(row[40+j]);
        float in = __bfloat162float(row[80+j]);
        float r = sigf(ir + bhh0[j]);
        float z = sigf(iz + bhh0[40+j]);
        float n = tanhfast(in + r*bhh0[80+j]);
        h0[j] = (1.0f - z)*n;
        h0_lds[j][threadIdx.x] = h0[j];
    }
    __hip_bfloat16* Prow = P + (size_t)m*KP_;
    int fbase = dir*HID_;
    if (dir){   // zero the K-pad 720..735 once per row
        short8 z8 = {0,0,0,0,0,0,0,0};
        *(short8*)((void*)&Prow[720]) = z8;
        *(short8*)((void*)&Prow[728]) = z8;
    }
    for (int j=0;j<HID_;j++){
        float gr = bhh1[j], gz = bhh1[40+j], gn = bhh1[80+j];
#pragma unroll
        for (int k=0;k<HID_;k++){
            float h = h0[k];
            gr += Whh1[j*HID_+k]      * h;
            gz += Whh1[(40+j)*HID_+k] * h;
            gn += Whh1[(80+j)*HID_+k] * h;
        }
        float ir = __bfloat162float(row[120+j]);
        float iz = __bfloat162float(row[160+j]);
        float in = __bfloat162float(row[200+j]);
        float r = sigf(ir + gr);
        float z = sigf(iz + gz);
        float n = tanhfast(in + r*gn);
        float h1 = (1.0f - z)*n + z*h0_lds[j][threadIdx.x];
        int fi = fbase + j;
        Prow[fi] = __float2bfloat16(h1 * sigf(h1));          // silu(feat)
        float bb8[8];
        bspline8(h1, bb8);
        short8 pk;
#pragma unroll
        for (int mm=0;mm<8;mm++) pk[mm] = bfbits(bb8[mm]);
        *(short8*)((void*)&Prow[80 + fi*8]) = pk;            // one 16B store
    }
}

// GEMM2 (MFMA): out[m,o] = 1.2*sigmoid(slope[o]*sum_k P[m,k]*Wk[o,k])
// block: 256 thr / 4 waves; M-tile 128 (2 sub/wave), full N (17 n-tiles) -> P read once
__global__ __launch_bounds__(256) void k3_gemm(const __hip_bfloat16* __restrict__ P,
                                               const __hip_bfloat16* __restrict__ Wk,
                                               const float* __restrict__ slope,
                                               float* __restrict__ outp){
    __shared__ __hip_bfloat16 Asm[128*40];
    __shared__ __hip_bfloat16 Bsm[NP_*40];
    int tid = threadIdx.x, wave = tid>>6, lane = tid&63;
    int m0 = blockIdx.x*128;
    f32x4 acc[2][17];
#pragma unroll
    for (int s=0;s<2;s++)
#pragma unroll
        for (int j=0;j<17;j++) acc[s][j] = (f32x4){0.f,0.f,0.f,0.f};

    for (int k0=0;k0<KP_;k0+=32){
#pragma unroll
        for (int p=0;p<2;p++){                    // A: 512 chunks of 16B
            int c = tid + p*256;
            int row = c>>2, kc = (c&3)*8;
            *(short8*)((void*)&Asm[row*40 + kc]) =
                *(const short8*)&P[(size_t)(m0+row)*KP_ + k0 + kc];
        }
#pragma unroll
        for (int p=0;p<5;p++){                    // B: 1088 chunks
            int c = tid + p*256;
            if (c < NP_*4){
                int row = c>>2, kc = (c&3)*8;
                *(short8*)((void*)&Bsm[row*40 + kc]) =
                    *(const short8*)&Wk[(size_t)row*KP_ + k0 + kc];
            }
        }
        __syncthreads();
        int kf = (lane>>4)*8, rl = lane&15;
        short8 a0 = *(short8*)((void*)&Asm[(wave*32 + rl)*40 + kf]);
        short8 a1 = *(short8*)((void*)&Asm[(wave*32 + 16 + rl)*40 + kf]);
#pragma unroll
        for (int j=0;j<17;j++){
            short8 b = *(short8*)((void*)&Bsm[(j*16 + rl)*40 + kf]);
            acc[0][j] = __builtin_amdgcn_mfma_f32_16x16x32_bf16(a0, b, acc[0][j], 0,0,0);
            acc[1][j] = __builtin_amdgcn_mfma_f32_16x16x32_bf16(a1, b, acc[1][j], 0,0,0);
        }
        __syncthreads();
    }
    int rl = lane&15, quad = lane>>4;
#pragma unroll
    for (int j=0;j<17;j++){
        int n = j*16 + rl;
        if (n < OUT_){
            float sl = slope[n];
#pragma unroll
            for (int s=0;s<2;s++){
                int mb = m0 + wave*32 + s*16 + quad*4;
#pragma unroll
                for (int r=0;r<4;r++)
                    outp[(size_t)(mb+r)*OUT_ + n] = 1.2f * sigf(sl*acc[s][j][r]);
            }
        }
    }
}

extern "C" void kernel_launch(void* const* d_in, const int* in_sizes, int n_in,
                              void* d_out, int out_size, void* d_ws, size_t ws_size,
                              hipStream_t stream) {
    const float* x      = (const float*)d_in[0];
    const float* Wih_f  = (const float*)d_in[1];
    const float* Whh_f  = (const float*)d_in[2];
    const float* bih_f  = (const float*)d_in[3];
    const float* bhh_f  = (const float*)d_in[4];
    const float* Wih_b  = (const float*)d_in[5];
    const float* Whh_b  = (const float*)d_in[6];
    const float* bih_b  = (const float*)d_in[7];
    const float* bhh_b  = (const float*)d_in[8];
    const float* base_w = (const float*)d_in[9];
    const float* spl_w  = (const float*)d_in[10];
    const float* spl_s  = (const float*)d_in[11];
    const float* slope  = (const float*)d_in[12];

    char* ws = (char*)d_ws;
    __hip_bfloat16* gi = (__hip_bfloat16*)ws;
    __hip_bfloat16* P  = (__hip_bfloat16*)(ws + OFF_P);
    __hip_bfloat16* Wk = (__hip_bfloat16*)(ws + OFF_WK);
    __hip_bfloat16* Wb = (__hip_bfloat16*)(ws + OFF_WB);
    float* outp = (float*)d_out;

    hipLaunchKernelGGL(kprep, dim3((NP_*(KP_/8) + 255)/256), dim3(256), 0, stream,
                       base_w, spl_w, spl_s, Wk);
    hipLaunchKernelGGL(wprep, dim3((NGI_*(KP1_/8) + 255)/256), dim3(256), 0, stream,
                       Wih_f, Wih_b, Wb);
    hipLaunchKernelGGL(k1_gemm, dim3(3, 500), dim3(256), 0, stream,
                       x, Wb, bih_f, bih_b, gi);
    hipLaunchKernelGGL(k2_gru, dim3(500), dim3(256), 0, stream,
                       gi, Whh_f, bhh_f, Whh_b, bhh_b, P);
    hipLaunchKernelGGL(k3_gemm, dim3(500), dim3(256), 0, stream,
                       P, Wk, slope, outp);
}

// Round 4
// 572.716 us; speedup vs baseline: 2.5612x; 1.1445x over previous
//
#include <hip/hip_runtime.h>
#include <hip/hip_bf16.h>

// Problem constants
#define B_    64
#define T_    1000
#define IN_   257
#define HID_  40
#define G3_   120
#define OUT_  257
#define M_    (B_*T_)   // 64000
#define NGI_  480
#define KP_   736       // padded KAN feature dim (720 real)
#define KP1_  288       // padded GEMM1 K (257 real)
#define NP_   272       // padded OUT_ for k3

// ws layout:
// gi0 64000x240 bf16 (layer0 gates, row-major; fwd 0..119 | bwd 120..239) = 30,720,000
// gi1 240x64000 bf16 (layer1 gates, col-major; fwd 0..119 | bwd 120..239) = 30,720,000
// P   64000x736 bf16 = 94,208,000
// Wk  272x736  bf16  =    400,384
// Wb  480x288  bf16  =    276,480
#define OFF_GI1 30720000ull
#define OFF_P   61440000ull
#define OFF_WK  (OFF_P + 94208000ull)
#define OFF_WB  (OFF_WK + 400384ull)

typedef __attribute__((ext_vector_type(8))) short bfx8;   // 8 bf16 = 4 VGPR
typedef __attribute__((ext_vector_type(4))) short bfx4;   // 8 B
typedef __attribute__((ext_vector_type(4))) float f32x4;  // MFMA C/D

__device__ __forceinline__ float sigf(float x){ return 1.0f/(1.0f + __expf(-x)); }
__device__ __forceinline__ float tanhfast(float x){ return 1.0f - 2.0f/(__expf(2.0f*x)+1.0f); }
__device__ __forceinline__ float gridp(int p){ return (float)(p-3)*0.4f - 1.0f; }

__device__ __forceinline__ void bspline8(float x, float* o){
    float b[11];
#pragma unroll
    for (int p=0;p<11;p++) b[p] = (x >= gridp(p) && x < gridp(p+1)) ? 1.0f : 0.0f;
#pragma unroll
    for (int k=1;k<=3;k++){
#pragma unroll
        for (int j=0;j<=10-k;j++){
            float gj=gridp(j), gjk=gridp(j+k), gjk1=gridp(j+k+1), gj1=gridp(j+1);
            b[j] = (x-gj)/(gjk-gj)*b[j] + (gjk1-x)/(gjk1-gj1)*b[j+1];
        }
    }
#pragma unroll
    for (int m=0;m<8;m++) o[m]=b[m];
}

__device__ __forceinline__ short bfbits(float v){
    __hip_bfloat16 h = __float2bfloat16(v);
    return *(short*)&h;
}
__device__ __forceinline__ float b2f(short s){
    return __uint_as_float(((unsigned)(unsigned short)s) << 16);
}

// Pack Wk[272][736] bf16
__global__ __launch_bounds__(256) void kprep(const float* __restrict__ bw,
                                             const float* __restrict__ sw,
                                             const float* __restrict__ ss,
                                             __hip_bfloat16* __restrict__ wk){
    int idx = blockIdx.x*256 + threadIdx.x;
    if (idx >= NP_*(KP_/8)) return;
    int o = idx / (KP_/8), q = idx % (KP_/8);
    bfx8 pk;
#pragma unroll
    for (int e=0;e<8;e++){
        int k = q*8 + e;
        float v = 0.0f;
        if (o < OUT_ && k < 720){
            if (k < 80) v = bw[o*80 + k];
            else { int i = (k-80)>>3, m = (k-80)&7; v = sw[(o*80+i)*8 + m] * ss[o*80+i]; }
        }
        pk[e] = bfbits(v);
    }
    *(bfx8*)((void*)&wk[(size_t)o*KP_ + q*8]) = pk;
}

// Pack Wb[480][288] bf16 from Wih_f | Wih_b
__global__ __launch_bounds__(256) void wprep(const float* __restrict__ Wf,
                                             const float* __restrict__ Wbk,
                                             __hip_bfloat16* __restrict__ wb){
    int idx = blockIdx.x*256 + threadIdx.x;
    if (idx >= NGI_*(KP1_/8)) return;
    int n = idx / (KP1_/8), q = idx % (KP1_/8);
    bfx8 pk;
#pragma unroll
    for (int e=0;e<8;e++){
        int k = q*8 + e;
        float v = 0.0f;
        if (k < IN_) v = (n < 240) ? Wf[(size_t)n*IN_ + k] : Wbk[(size_t)(n-240)*IN_ + k];
        pk[e] = bfbits(v);
    }
    *(bfx8*)((void*)&wb[(size_t)n*KP1_ + q*8]) = pk;
}

// GEMM1 (MFMA): routes layer0 gates -> gi0[m][240] row-major, layer1 gates -> gi1[gate][m] col-major
__global__ __launch_bounds__(256) void k1_gemm(const float* __restrict__ X,
                                               const __hip_bfloat16* __restrict__ Wb16,
                                               const float* __restrict__ bf,
                                               const float* __restrict__ bb,
                                               __hip_bfloat16* __restrict__ gi0,
                                               __hip_bfloat16* __restrict__ gi1){
    __shared__ __hip_bfloat16 Asm[128*40];
    __shared__ __hip_bfloat16 Bsm[160*40];
    int tid = threadIdx.x, wave = tid>>6, lane = tid&63;
    int m0 = blockIdx.y*128, n0 = blockIdx.x*160;
    f32x4 acc[2][10];
#pragma unroll
    for (int s=0;s<2;s++)
#pragma unroll
        for (int j=0;j<10;j++) acc[s][j] = (f32x4){0.f,0.f,0.f,0.f};

    for (int k0=0;k0<KP1_;k0+=32){
#pragma unroll
        for (int p=0;p<2;p++){
            int c = tid + p*256;
            int row = c>>2, kc = (c&3)*8;
            bfx8 pk;
#pragma unroll
            for (int e=0;e<8;e++){
                int k = k0 + kc + e;
                float v = (k < IN_) ? X[(size_t)(m0+row)*IN_ + k] : 0.0f;
                pk[e] = bfbits(v);
            }
            *(bfx8*)((void*)&Asm[row*40 + kc]) = pk;
        }
#pragma unroll
        for (int p=0;p<3;p++){
            int c = tid + p*256;
            if (c < 640){
                int row = c>>2, kc = (c&3)*8;
                *(bfx8*)((void*)&Bsm[row*40 + kc]) =
                    *(const bfx8*)&Wb16[(size_t)(n0+row)*KP1_ + k0 + kc];
            }
        }
        __syncthreads();
        int kf = (lane>>4)*8, rl = lane&15;
        bfx8 a0 = *(bfx8*)((void*)&Asm[(wave*32 + rl)*40 + kf]);
        bfx8 a1 = *(bfx8*)((void*)&Asm[(wave*32 + 16 + rl)*40 + kf]);
#pragma unroll
        for (int j=0;j<10;j++){
            bfx8 b = *(bfx8*)((void*)&Bsm[(j*16 + rl)*40 + kf]);
            acc[0][j] = __builtin_amdgcn_mfma_f32_16x16x32_bf16(a0, b, acc[0][j], 0,0,0);
            acc[1][j] = __builtin_amdgcn_mfma_f32_16x16x32_bf16(a1, b, acc[1][j], 0,0,0);
        }
        __syncthreads();
    }
    int rl = lane&15, quad = lane>>4;
#pragma unroll
    for (int j=0;j<10;j++){
        int n = n0 + j*16 + rl;
        float bias = (n < 240) ? bf[n] : bb[n-240];
        int d  = (n >= 240) ? 1 : 0;
        int nn = n - 240*d;
#pragma unroll
        for (int s=0;s<2;s++){
            int mb = m0 + wave*32 + s*16 + quad*4;
            if (nn < 120){            // layer0 gate -> gi0 row-major
#pragma unroll
                for (int r=0;r<4;r++)
                    gi0[(size_t)(mb+r)*240 + d*120 + nn] = __float2bfloat16(acc[s][j][r] + bias);
            } else {                  // layer1 gate -> gi1 col-major (8B vector store)
                bfx4 v;
#pragma unroll
                for (int r=0;r<4;r++) v[r] = bfbits(acc[s][j][r] + bias);
                *(bfx4*)((void*)&gi1[(size_t)(d*120 + nn - 120)*M_ + mb]) = v;
            }
        }
    }
}

// Pointwise GRU + feature build -> P(64000x736 bf16). 64-thr blocks; dir block-uniform.
__global__ __launch_bounds__(64) void k2_gru(const __hip_bfloat16* __restrict__ gi0,
                                             const __hip_bfloat16* __restrict__ gi1,
                                             const float* __restrict__ Whh_f,
                                             const float* __restrict__ bhh_f,
                                             const float* __restrict__ Whh_b,
                                             const float* __restrict__ bhh_b,
                                             __hip_bfloat16* __restrict__ P){
    __shared__ float h0_lds[HID_][64];
    int tid = threadIdx.x;
    int dir = (blockIdx.x >= 1000) ? 1 : 0;
    int m = (blockIdx.x - dir*1000)*64 + tid;
    int b = m / T_, t = m % T_;
    int src = dir ? (b*T_ + (T_-1-t)) : m;
    const float* Whh1  = (dir ? Whh_b : Whh_f) + G3_*HID_;
    const float* bhh0v = dir ? bhh_b : bhh_f;
    const float* bhh1  = bhh0v + G3_;

    // ---- layer 0: 15 x 16B vector loads, fully register-resident ----
    const bfx8* g0 = (const bfx8*)(gi0 + (size_t)src*240 + dir*120);
    bfx8 c[15];
#pragma unroll
    for (int q=0;q<15;q++) c[q] = g0[q];
    float h0[HID_];
#pragma unroll
    for (int j=0;j<HID_;j++){
        float ir = b2f(c[j>>3][j&7]);
        float iz = b2f(c[(40+j)>>3][(40+j)&7]);
        float in = b2f(c[(80+j)>>3][(80+j)&7]);
        float r = sigf(ir + bhh0v[j]);
        float z = sigf(iz + bhh0v[40+j]);
        float n = tanhfast(in + r*bhh0v[80+j]);
        h0[j] = (1.0f - z)*n;
        h0_lds[j][tid] = h0[j];
    }

    __hip_bfloat16* Prow = P + (size_t)m*KP_;
    if (dir){   // zero K-pad 720..735
        bfx8 z8 = {0,0,0,0,0,0,0,0};
        *(bfx8*)((void*)&Prow[720]) = z8;
        *(bfx8*)((void*)&Prow[728]) = z8;
    }
    const __hip_bfloat16* g1 = gi1 + (size_t)(dir*120)*M_ + src;

    // ---- layer 1: 5 x (8 unrolled features); gi1 reads coalesced ----
    for (int jo=0;jo<5;jo++){
        bfx8 sil;
#pragma unroll
        for (int jj=0;jj<8;jj++){
            int j = jo*8 + jj;
            float gr = bhh1[j], gz = bhh1[40+j], gn = bhh1[80+j];
#pragma unroll
            for (int k=0;k<HID_;k++){
                float h = h0[k];
                gr += Whh1[j*HID_+k]      * h;
                gz += Whh1[(40+j)*HID_+k] * h;
                gn += Whh1[(80+j)*HID_+k] * h;
            }
            float ir = b2f(*(const short*)&g1[(size_t)j*M_]);
            float iz = b2f(*(const short*)&g1[(size_t)(40+j)*M_]);
            float in = b2f(*(const short*)&g1[(size_t)(80+j)*M_]);
            float r = sigf(ir + gr);
            float z = sigf(iz + gz);
            float n = tanhfast(in + r*gn);
            float h1 = (1.0f - z)*n + z*h0_lds[j][tid];
            sil[jj] = bfbits(h1 * sigf(h1));
            float bb8[8];
            bspline8(h1, bb8);
            bfx8 pk;
#pragma unroll
            for (int mm=0;mm<8;mm++) pk[mm] = bfbits(bb8[mm]);
            *(bfx8*)((void*)&Prow[80 + (dir*HID_ + j)*8]) = pk;
        }
        *(bfx8*)((void*)&Prow[dir*HID_ + jo*8]) = sil;
    }
}

// GEMM2 (MFMA): out[m,o] = 1.2*sigmoid(slope[o]*sum_k P[m,k]*Wk[o,k])
__global__ __launch_bounds__(256) void k3_gemm(const __hip_bfloat16* __restrict__ P,
                                               const __hip_bfloat16* __restrict__ Wk,
                                               const float* __restrict__ slope,
                                               float* __restrict__ outp){
    __shared__ __hip_bfloat16 Asm[128*40];
    __shared__ __hip_bfloat16 Bsm[NP_*40];
    int tid = threadIdx.x, wave = tid>>6, lane = tid&63;
    int m0 = blockIdx.x*128;
    f32x4 acc[2][17];
#pragma unroll
    for (int s=0;s<2;s++)
#pragma unroll
        for (int j=0;j<17;j++) acc[s][j] = (f32x4){0.f,0.f,0.f,0.f};

    for (int k0=0;k0<KP_;k0+=32){
#pragma unroll
        for (int p=0;p<2;p++){
            int c = tid + p*256;
            int row = c>>2, kc = (c&3)*8;
            *(bfx8*)((void*)&Asm[row*40 + kc]) =
                *(const bfx8*)&P[(size_t)(m0+row)*KP_ + k0 + kc];
        }
#pragma unroll
        for (int p=0;p<5;p++){
            int c = tid + p*256;
            if (c < NP_*4){
                int row = c>>2, kc = (c&3)*8;
                *(bfx8*)((void*)&Bsm[row*40 + kc]) =
                    *(const bfx8*)&Wk[(size_t)row*KP_ + k0 + kc];
            }
        }
        __syncthreads();
        int kf = (lane>>4)*8, rl = lane&15;
        bfx8 a0 = *(bfx8*)((void*)&Asm[(wave*32 + rl)*40 + kf]);
        bfx8 a1 = *(bfx8*)((void*)&Asm[(wave*32 + 16 + rl)*40 + kf]);
#pragma unroll
        for (int j=0;j<17;j++){
            bfx8 b = *(bfx8*)((void*)&Bsm[(j*16 + rl)*40 + kf]);
            acc[0][j] = __builtin_amdgcn_mfma_f32_16x16x32_bf16(a0, b, acc[0][j], 0,0,0);
            acc[1][j] = __builtin_amdgcn_mfma_f32_16x16x32_bf16(a1, b, acc[1][j], 0,0,0);
        }
        __syncthreads();
    }
    int rl = lane&15, quad = lane>>4;
#pragma unroll
    for (int j=0;j<17;j++){
        int n = j*16 + rl;
        if (n < OUT_){
            float sl = slope[n];
#pragma unroll
            for (int s=0;s<2;s++){
                int mb = m0 + wave*32 + s*16 + quad*4;
#pragma unroll
                for (int r=0;r<4;r++)
                    outp[(size_t)(mb+r)*OUT_ + n] = 1.2f * sigf(sl*acc[s][j][r]);
            }
        }
    }
}

extern "C" void kernel_launch(void* const* d_in, const int* in_sizes, int n_in,
                              void* d_out, int out_size, void* d_ws, size_t ws_size,
                              hipStream_t stream) {
    const float* x      = (const float*)d_in[0];
    const float* Wih_f  = (const float*)d_in[1];
    const float* Whh_f  = (const float*)d_in[2];
    const float* bih_f  = (const float*)d_in[3];
    const float* bhh_f  = (const float*)d_in[4];
    const float* Wih_b  = (const float*)d_in[5];
    const float* Whh_b  = (const float*)d_in[6];
    const float* bih_b  = (const float*)d_in[7];
    const float* bhh_b  = (const float*)d_in[8];
    const float* base_w = (const float*)d_in[9];
    const float* spl_w  = (const float*)d_in[10];
    const float* spl_s  = (const float*)d_in[11];
    const float* slope  = (const float*)d_in[12];

    char* ws = (char*)d_ws;
    __hip_bfloat16* gi0 = (__hip_bfloat16*)ws;
    __hip_bfloat16* gi1 = (__hip_bfloat16*)(ws + OFF_GI1);
    __hip_bfloat16* P   = (__hip_bfloat16*)(ws + OFF_P);
    __hip_bfloat16* Wk  = (__hip_bfloat16*)(ws + OFF_WK);
    __hip_bfloat16* Wb  = (__hip_bfloat16*)(ws + OFF_WB);
    float* outp = (float*)d_out;

    hipLaunchKernelGGL(kprep, dim3((NP_*(KP_/8) + 255)/256), dim3(256), 0, stream,
                       base_w, spl_w, spl_s, Wk);
    hipLaunchKernelGGL(wprep, dim3((NGI_*(KP1_/8) + 255)/256), dim3(256), 0, stream,
                       Wih_f, Wih_b, Wb);
    hipLaunchKernelGGL(k1_gemm, dim3(3, 500), dim3(256), 0, stream,
                       x, Wb, bih_f, bih_b, gi0, gi1);
    hipLaunchKernelGGL(k2_gru, dim3(2000), dim3(64), 0, stream,
                       gi0, gi1, Whh_f, bhh_f, Whh_b, bhh_b, P);
    hipLaunchKernelGGL(k3_gemm, dim3(500), dim3(256), 0, stream,
                       P, Wk, slope, outp);
}

// Round 5
// 571.741 us; speedup vs baseline: 2.5655x; 1.0017x over previous
//
#include <hip/hip_runtime.h>
#include <hip/hip_bf16.h>

// Problem constants
#define B_    64
#define T_    1000
#define IN_   257
#define HID_  40
#define G3_   120
#define OUT_  257
#define M_    (B_*T_)   // 64000
#define NGI_  480
#define KP_   736       // padded KAN feature dim (720 real)
#define KP1_  288       // padded GEMM1 K (257 real)
#define NP_   272       // padded OUT_ for k3

// ws layout:
// gi0 64000x240 bf16 (layer0 gates, row-major; fwd 0..119 | bwd 120..239) = 30,720,000
// gi1 240x64000 bf16 (layer1 gates, col-major; fwd 0..119 | bwd 120..239) = 30,720,000
// P   64000x736 bf16 = 94,208,000
// Wk  272x736  bf16  =    400,384
// Wb  480x288  bf16  =    276,480
#define OFF_GI1 30720000ull
#define OFF_P   61440000ull
#define OFF_WK  (OFF_P + 94208000ull)
#define OFF_WB  (OFF_WK + 400384ull)

typedef __attribute__((ext_vector_type(8))) short bfx8;   // 8 bf16 = 4 VGPR
typedef __attribute__((ext_vector_type(4))) short bfx4;   // 8 B
typedef __attribute__((ext_vector_type(4))) float f32x4;  // MFMA C/D

__device__ __forceinline__ float sigf(float x){ return 1.0f/(1.0f + __expf(-x)); }
__device__ __forceinline__ float tanhfast(float x){ return 1.0f - 2.0f/(__expf(2.0f*x)+1.0f); }
__device__ __forceinline__ float gridp(int p){ return (float)(p-3)*0.4f - 1.0f; }

__device__ __forceinline__ void bspline8(float x, float* o){
    float b[11];
#pragma unroll
    for (int p=0;p<11;p++) b[p] = (x >= gridp(p) && x < gridp(p+1)) ? 1.0f : 0.0f;
#pragma unroll
    for (int k=1;k<=3;k++){
#pragma unroll
        for (int j=0;j<=10-k;j++){
            float gj=gridp(j), gjk=gridp(j+k), gjk1=gridp(j+k+1), gj1=gridp(j+1);
            b[j] = (x-gj)/(gjk-gj)*b[j] + (gjk1-x)/(gjk1-gj1)*b[j+1];
        }
    }
#pragma unroll
    for (int m=0;m<8;m++) o[m]=b[m];
}

__device__ __forceinline__ short bfbits(float v){
    __hip_bfloat16 h = __float2bfloat16(v);
    return *(short*)&h;
}
__device__ __forceinline__ float b2f(short s){
    return __uint_as_float(((unsigned)(unsigned short)s) << 16);
}

// Pack Wk[272][736] bf16
__global__ __launch_bounds__(256) void kprep(const float* __restrict__ bw,
                                             const float* __restrict__ sw,
                                             const float* __restrict__ ss,
                                             __hip_bfloat16* __restrict__ wk){
    int idx = blockIdx.x*256 + threadIdx.x;
    if (idx >= NP_*(KP_/8)) return;
    int o = idx / (KP_/8), q = idx % (KP_/8);
    bfx8 pk;
#pragma unroll
    for (int e=0;e<8;e++){
        int k = q*8 + e;
        float v = 0.0f;
        if (o < OUT_ && k < 720){
            if (k < 80) v = bw[o*80 + k];
            else { int i = (k-80)>>3, m = (k-80)&7; v = sw[(o*80+i)*8 + m] * ss[o*80+i]; }
        }
        pk[e] = bfbits(v);
    }
    *(bfx8*)((void*)&wk[(size_t)o*KP_ + q*8]) = pk;
}

// Pack Wb[480][288] bf16 from Wih_f | Wih_b
__global__ __launch_bounds__(256) void wprep(const float* __restrict__ Wf,
                                             const float* __restrict__ Wbk,
                                             __hip_bfloat16* __restrict__ wb){
    int idx = blockIdx.x*256 + threadIdx.x;
    if (idx >= NGI_*(KP1_/8)) return;
    int n = idx / (KP1_/8), q = idx % (KP1_/8);
    bfx8 pk;
#pragma unroll
    for (int e=0;e<8;e++){
        int k = q*8 + e;
        float v = 0.0f;
        if (k < IN_) v = (n < 240) ? Wf[(size_t)n*IN_ + k] : Wbk[(size_t)(n-240)*IN_ + k];
        pk[e] = bfbits(v);
    }
    *(bfx8*)((void*)&wb[(size_t)n*KP1_ + q*8]) = pk;
}

// GEMM1 (MFMA): routes layer0 gates -> gi0[m][240] row-major, layer1 gates -> gi1[gate][m] col-major
__global__ __launch_bounds__(256) void k1_gemm(const float* __restrict__ X,
                                               const __hip_bfloat16* __restrict__ Wb16,
                                               const float* __restrict__ bf,
                                               const float* __restrict__ bb,
                                               __hip_bfloat16* __restrict__ gi0,
                                               __hip_bfloat16* __restrict__ gi1){
    __shared__ __hip_bfloat16 Asm[128*40];
    __shared__ __hip_bfloat16 Bsm[160*40];
    int tid = threadIdx.x, wave = tid>>6, lane = tid&63;
    int m0 = blockIdx.y*128, n0 = blockIdx.x*160;
    f32x4 acc[2][10];
#pragma unroll
    for (int s=0;s<2;s++)
#pragma unroll
        for (int j=0;j<10;j++) acc[s][j] = (f32x4){0.f,0.f,0.f,0.f};

    for (int k0=0;k0<KP1_;k0+=32){
#pragma unroll
        for (int p=0;p<2;p++){
            int c = tid + p*256;
            int row = c>>2, kc = (c&3)*8;
            bfx8 pk;
#pragma unroll
            for (int e=0;e<8;e++){
                int k = k0 + kc + e;
                float v = (k < IN_) ? X[(size_t)(m0+row)*IN_ + k] : 0.0f;
                pk[e] = bfbits(v);
            }
            *(bfx8*)((void*)&Asm[row*40 + kc]) = pk;
        }
#pragma unroll
        for (int p=0;p<3;p++){
            int c = tid + p*256;
            if (c < 640){
                int row = c>>2, kc = (c&3)*8;
                *(bfx8*)((void*)&Bsm[row*40 + kc]) =
                    *(const bfx8*)&Wb16[(size_t)(n0+row)*KP1_ + k0 + kc];
            }
        }
        __syncthreads();
        int kf = (lane>>4)*8, rl = lane&15;
        bfx8 a0 = *(bfx8*)((void*)&Asm[(wave*32 + rl)*40 + kf]);
        bfx8 a1 = *(bfx8*)((void*)&Asm[(wave*32 + 16 + rl)*40 + kf]);
#pragma unroll
        for (int j=0;j<10;j++){
            bfx8 b = *(bfx8*)((void*)&Bsm[(j*16 + rl)*40 + kf]);
            acc[0][j] = __builtin_amdgcn_mfma_f32_16x16x32_bf16(a0, b, acc[0][j], 0,0,0);
            acc[1][j] = __builtin_amdgcn_mfma_f32_16x16x32_bf16(a1, b, acc[1][j], 0,0,0);
        }
        __syncthreads();
    }
    int rl = lane&15, quad = lane>>4;
#pragma unroll
    for (int j=0;j<10;j++){
        int n = n0 + j*16 + rl;
        float bias = (n < 240) ? bf[n] : bb[n-240];
        int d  = (n >= 240) ? 1 : 0;
        int nn = n - 240*d;
#pragma unroll
        for (int s=0;s<2;s++){
            int mb = m0 + wave*32 + s*16 + quad*4;
            if (nn < 120){            // layer0 gate -> gi0 row-major
#pragma unroll
                for (int r=0;r<4;r++)
                    gi0[(size_t)(mb+r)*240 + d*120 + nn] = __float2bfloat16(acc[s][j][r] + bias);
            } else {                  // layer1 gate -> gi1 col-major (8B vector store)
                bfx4 v;
#pragma unroll
                for (int r=0;r<4;r++) v[r] = bfbits(acc[s][j][r] + bias);
                *(bfx4*)((void*)&gi1[(size_t)(d*120 + nn - 120)*M_ + mb]) = v;
            }
        }
    }
}

// Pointwise GRU + feature build -> P(64000x736 bf16). 64-thr blocks; dir block-uniform.
// (64,2): min 2 waves/EU -> VGPR cap 256; keeps c[15]+h0[40] in registers (was spilling at 52 VGPR)
__global__ __launch_bounds__(64, 2) void k2_gru(const __hip_bfloat16* __restrict__ gi0,
                                             const __hip_bfloat16* __restrict__ gi1,
                                             const float* __restrict__ Whh_f,
                                             const float* __restrict__ bhh_f,
                                             const float* __restrict__ Whh_b,
                                             const float* __restrict__ bhh_b,
                                             __hip_bfloat16* __restrict__ P){
    __shared__ float h0_lds[HID_][64];
    int tid = threadIdx.x;
    int dir = (blockIdx.x >= 1000) ? 1 : 0;
    int m = (blockIdx.x - dir*1000)*64 + tid;
    int b = m / T_, t = m % T_;
    int src = dir ? (b*T_ + (T_-1-t)) : m;
    const float* Whh1  = (dir ? Whh_b : Whh_f) + G3_*HID_;
    const float* bhh0v = dir ? bhh_b : bhh_f;
    const float* bhh1  = bhh0v + G3_;

    // ---- layer 0: 15 x 16B vector loads, fully register-resident ----
    const bfx8* g0 = (const bfx8*)(gi0 + (size_t)src*240 + dir*120);
    bfx8 c[15];
#pragma unroll
    for (int q=0;q<15;q++) c[q] = g0[q];
    float h0[HID_];
#pragma unroll
    for (int j=0;j<HID_;j++){
        float ir = b2f(c[j>>3][j&7]);
        float iz = b2f(c[(40+j)>>3][(40+j)&7]);
        float in = b2f(c[(80+j)>>3][(80+j)&7]);
        float r = sigf(ir + bhh0v[j]);
        float z = sigf(iz + bhh0v[40+j]);
        float n = tanhfast(in + r*bhh0v[80+j]);
        h0[j] = (1.0f - z)*n;
        h0_lds[j][tid] = h0[j];
    }

    __hip_bfloat16* Prow = P + (size_t)m*KP_;
    if (dir){   // zero K-pad 720..735
        bfx8 z8 = {0,0,0,0,0,0,0,0};
        *(bfx8*)((void*)&Prow[720]) = z8;
        *(bfx8*)((void*)&Prow[728]) = z8;
    }
    const __hip_bfloat16* g1 = gi1 + (size_t)(dir*120)*M_ + src;

    // ---- layer 1: 5 x (8 unrolled features); gi1 reads coalesced ----
    for (int jo=0;jo<5;jo++){
        bfx8 sil;
#pragma unroll
        for (int jj=0;jj<8;jj++){
            int j = jo*8 + jj;
            float gr = bhh1[j], gz = bhh1[40+j], gn = bhh1[80+j];
#pragma unroll
            for (int k=0;k<HID_;k++){
                float h = h0[k];
                gr += Whh1[j*HID_+k]      * h;
                gz += Whh1[(40+j)*HID_+k] * h;
                gn += Whh1[(80+j)*HID_+k] * h;
            }
            float ir = b2f(*(const short*)&g1[(size_t)j*M_]);
            float iz = b2f(*(const short*)&g1[(size_t)(40+j)*M_]);
            float in = b2f(*(const short*)&g1[(size_t)(80+j)*M_]);
            float r = sigf(ir + gr);
            float z = sigf(iz + gz);
            float n = tanhfast(in + r*gn);
            float h1 = (1.0f - z)*n + z*h0_lds[j][tid];
            sil[jj] = bfbits(h1 * sigf(h1));
            float bb8[8];
            bspline8(h1, bb8);
            bfx8 pk;
#pragma unroll
            for (int mm=0;mm<8;mm++) pk[mm] = bfbits(bb8[mm]);
            *(bfx8*)((void*)&Prow[80 + (dir*HID_ + j)*8]) = pk;
        }
        *(bfx8*)((void*)&Prow[dir*HID_ + jo*8]) = sil;
    }
}

// GEMM2 (MFMA): out[m,o] = 1.2*sigmoid(slope[o]*sum_k P[m,k]*Wk[o,k])
__global__ __launch_bounds__(256) void k3_gemm(const __hip_bfloat16* __restrict__ P,
                                               const __hip_bfloat16* __restrict__ Wk,
                                               const float* __restrict__ slope,
                                               float* __restrict__ outp){
    __shared__ __hip_bfloat16 Asm[128*40];
    __shared__ __hip_bfloat16 Bsm[NP_*40];
    int tid = threadIdx.x, wave = tid>>6, lane = tid&63;
    int m0 = blockIdx.x*128;
    f32x4 acc[2][17];
#pragma unroll
    for (int s=0;s<2;s++)
#pragma unroll
        for (int j=0;j<17;j++) acc[s][j] = (f32x4){0.f,0.f,0.f,0.f};

    for (int k0=0;k0<KP_;k0+=32){
#pragma unroll
        for (int p=0;p<2;p++){
            int c = tid + p*256;
            int row = c>>2, kc = (c&3)*8;
            *(bfx8*)((void*)&Asm[row*40 + kc]) =
                *(const bfx8*)&P[(size_t)(m0+row)*KP_ + k0 + kc];
        }
#pragma unroll
        for (int p=0;p<5;p++){
            int c = tid + p*256;
            if (c < NP_*4){
                int row = c>>2, kc = (c&3)*8;
                *(bfx8*)((void*)&Bsm[row*40 + kc]) =
                    *(const bfx8*)&Wk[(size_t)row*KP_ + k0 + kc];
            }
        }
        __syncthreads();
        int kf = (lane>>4)*8, rl = lane&15;
        bfx8 a0 = *(bfx8*)((void*)&Asm[(wave*32 + rl)*40 + kf]);
        bfx8 a1 = *(bfx8*)((void*)&Asm[(wave*32 + 16 + rl)*40 + kf]);
#pragma unroll
        for (int j=0;j<17;j++){
            bfx8 b = *(bfx8*)((void*)&Bsm[(j*16 + rl)*40 + kf]);
            acc[0][j] = __builtin_amdgcn_mfma_f32_16x16x32_bf16(a0, b, acc[0][j], 0,0,0);
            acc[1][j] = __builtin_amdgcn_mfma_f32_16x16x32_bf16(a1, b, acc[1][j], 0,0,0);
        }
        __syncthreads();
    }
    int rl = lane&15, quad = lane>>4;
#pragma unroll
    for (int j=0;j<17;j++){
        int n = j*16 + rl;
        if (n < OUT_){
            float sl = slope[n];
#pragma unroll
            for (int s=0;s<2;s++){
                int mb = m0 + wave*32 + s*16 + quad*4;
#pragma unroll
                for (int r=0;r<4;r++)
                    outp[(size_t)(mb+r)*OUT_ + n] = 1.2f * sigf(sl*acc[s][j][r]);
            }
        }
    }
}

extern "C" void kernel_launch(void* const* d_in, const int* in_sizes, int n_in,
                              void* d_out, int out_size, void* d_ws, size_t ws_size,
                              hipStream_t stream) {
    const float* x      = (const float*)d_in[0];
    const float* Wih_f  = (const float*)d_in[1];
    const float* Whh_f  = (const float*)d_in[2];
    const float* bih_f  = (const float*)d_in[3];
    const float* bhh_f  = (const float*)d_in[4];
    const float* Wih_b  = (const float*)d_in[5];
    const float* Whh_b  = (const float*)d_in[6];
    const float* bih_b  = (const float*)d_in[7];
    const float* bhh_b  = (const float*)d_in[8];
    const float* base_w = (const float*)d_in[9];
    const float* spl_w  = (const float*)d_in[10];
    const float* spl_s  = (const float*)d_in[11];
    const float* slope  = (const float*)d_in[12];

    char* ws = (char*)d_ws;
    __hip_bfloat16* gi0 = (__hip_bfloat16*)ws;
    __hip_bfloat16* gi1 = (__hip_bfloat16*)(ws + OFF_GI1);
    __hip_bfloat16* P   = (__hip_bfloat16*)(ws + OFF_P);
    __hip_bfloat16* Wk  = (__hip_bfloat16*)(ws + OFF_WK);
    __hip_bfloat16* Wb  = (__hip_bfloat16*)(ws + OFF_WB);
    float* outp = (float*)d_out;

    hipLaunchKernelGGL(kprep, dim3((NP_*(KP_/8) + 255)/256), dim3(256), 0, stream,
                       base_w, spl_w, spl_s, Wk);
    hipLaunchKernelGGL(wprep, dim3((NGI_*(KP1_/8) + 255)/256), dim3(256), 0, stream,
                       Wih_f, Wih_b, Wb);
    hipLaunchKernelGGL(k1_gemm, dim3(3, 500), dim3(256), 0, stream,
                       x, Wb, bih_f, bih_b, gi0, gi1);
    hipLaunchKernelGGL(k2_gru, dim3(2000), dim3(64), 0, stream,
                       gi0, gi1, Whh_f, bhh_f, Whh_b, bhh_b, P);
    hipLaunchKernelGGL(k3_gemm, dim3(500), dim3(256), 0, stream,
                       P, Wk, slope, outp);
}